// Round 1
// baseline (239.462 us; speedup 1.0000x reference)
//
#include <hip/hip_runtime.h>
#include <hip/hip_bf16.h>

// Problem constants (from reference): N=65536 rows, A=512 features, C=1000 classes.
constexpr int N_ROWS = 65536;
constexpr int N_FEAT = 512;
constexpr int N_FEAT2 = N_FEAT / 2;   // float2 elements per row = 256
constexpr int N_CLS  = 1000;
constexpr int CLS_PAD = 1024;         // padded bins for scan kernel

// Workspace layout (bytes):
//   [0,       4096)   int nc[1024]      per-class counts   (zeroed via memsetAsync)
//   [4096,    8192)   int offs[1024]    exclusive prefix offsets
//   [8192,   12288)   int cursor[1024]  scatter cursors
//   [12288, 274432)   int perm[65536]   row indices grouped by class
// total 268 KB

__global__ void hist_kernel(const int* __restrict__ labels, int* __restrict__ nc, int n) {
    int i = blockIdx.x * blockDim.x + threadIdx.x;
    if (i < n) atomicAdd(&nc[labels[i]], 1);
}

__global__ void scan_kernel(const int* __restrict__ nc,
                            int* __restrict__ offs, int* __restrict__ cursor) {
    __shared__ int tmp[CLS_PAD];
    int t = threadIdx.x;
    int v = (t < N_CLS) ? nc[t] : 0;
    tmp[t] = v;
    __syncthreads();
    // Hillis-Steele inclusive scan over 1024 elements
    for (int d = 1; d < CLS_PAD; d <<= 1) {
        int x = (t >= d) ? tmp[t - d] : 0;
        __syncthreads();
        tmp[t] += x;
        __syncthreads();
    }
    int excl = tmp[t] - v;
    if (t < N_CLS) { offs[t] = excl; cursor[t] = excl; }
}

__global__ void scatter_kernel(const int* __restrict__ labels,
                               int* __restrict__ cursor, int* __restrict__ perm, int n) {
    int i = blockIdx.x * blockDim.x + threadIdx.x;
    if (i < n) {
        int c = labels[i];
        int pos = atomicAdd(&cursor[c], 1);
        perm[pos] = i;
    }
}

// One block per class; 256 threads, each owns 2 columns (float2).
// Each inner-loop iteration reads one full contiguous 2 KB feature row — fully
// coalesced; #pragma unroll 4 keeps 4 independent row loads in flight.
__global__ __launch_bounds__(256) void estimator_main(
    const float* __restrict__ features,
    const float* __restrict__ count,
    const float* __restrict__ mean,
    const float* __restrict__ cov,
    const int* __restrict__ nc,
    const int* __restrict__ offs,
    const int* __restrict__ perm,
    float* __restrict__ out) {
    const int c = blockIdx.x;
    const int t = threadIdx.x;
    const int n = nc[c];
    const int start = offs[c];

    __shared__ int lrows[256];
    const float2* __restrict__ f2 = (const float2*)features;

    float sx = 0.f, sy = 0.f, qx = 0.f, qy = 0.f;

    for (int base = 0; base < n; base += 256) {
        int chunk = min(256, n - base);
        __syncthreads();
        if (t < chunk) lrows[t] = perm[start + base + t];
        __syncthreads();
        #pragma unroll 4
        for (int j = 0; j < chunk; ++j) {
            int r = lrows[j];                       // LDS broadcast (free)
            float2 v = f2[(size_t)r * N_FEAT2 + t]; // contiguous 2 KB per block
            sx += v.x; sy += v.y;
            qx += v.x * v.x; qy += v.y * v.y;
        }
    }

    const float fn  = (float)n;
    const float amt = (n > 0) ? fn : 1.0f;
    const float inv = 1.0f / amt;
    const float avx = sx * inv, avy = sy * inv;
    const float vrx = qx * inv - avx * avx;
    const float vry = qy * inv - avy * avy;

    const float cnt   = count[c];
    const float denom = fn + cnt;
    const float w     = (denom == 0.f) ? 0.f : fn / denom;
    const float omw   = 1.0f - w;

    const float2 mv = ((const float2*)mean)[c * N_FEAT2 + t];
    const float2 cv = ((const float2*)cov)[c * N_FEAT2 + t];
    const float dx = mv.x - avx, dy = mv.y - avy;

    float2 covn, meann;
    covn.x  = cv.x * omw + vrx * w + w * omw * dx * dx;
    covn.y  = cv.y * omw + vry * w + w * omw * dy * dy;
    meann.x = mv.x * omw + avx * w;
    meann.y = mv.y * omw + avy * w;

    float2* outc = (float2*)out;                          // cov_new  [C*A]
    float2* outm = (float2*)(out + N_CLS * N_FEAT);       // mean_new [C*A]
    outc[c * N_FEAT2 + t] = covn;
    outm[c * N_FEAT2 + t] = meann;
    if (t == 0) out[2 * N_CLS * N_FEAT + c] = cnt + fn;   // count_new [C]
}

extern "C" void kernel_launch(void* const* d_in, const int* in_sizes, int n_in,
                              void* d_out, int out_size, void* d_ws, size_t ws_size,
                              hipStream_t stream) {
    const float* features = (const float*)d_in[0];
    const int*   labels   = (const int*)d_in[1];
    const float* count    = (const float*)d_in[2];
    const float* mean     = (const float*)d_in[3];
    const float* cov      = (const float*)d_in[4];
    float* out = (float*)d_out;

    char* ws = (char*)d_ws;
    int* nc     = (int*)(ws + 0);
    int* offs   = (int*)(ws + 4096);
    int* cursor = (int*)(ws + 8192);
    int* perm   = (int*)(ws + 12288);

    // zero the histogram bins (ws is poisoned 0xAA each call)
    hipMemsetAsync(nc, 0, CLS_PAD * sizeof(int), stream);

    hist_kernel<<<(N_ROWS + 255) / 256, 256, 0, stream>>>(labels, nc, N_ROWS);
    scan_kernel<<<1, CLS_PAD, 0, stream>>>(nc, offs, cursor);
    scatter_kernel<<<(N_ROWS + 255) / 256, 256, 0, stream>>>(labels, cursor, perm, N_ROWS);
    estimator_main<<<N_CLS, 256, 0, stream>>>(features, count, mean, cov,
                                              nc, offs, perm, out);
}